// Round 8
// baseline (323.816 us; speedup 1.0000x reference)
//
#include <hip/hip_runtime.h>

// ---------------------------------------------------------------------------
// GraphTransformerWithPooling on MI355X (gfx950)
// R8: algebraic collapse of each 2-layer pool block:
//     pool2(x) = S^2 x * W^2 + (S d)(b^T W) + d b^T      (S = agg matrix,
//     d = in-degree). W^2 precomputed in prep (fp32 dot per frag element).
//     Final GEMM chained inside the last fused kernel (LDS C->A round-trip).
// Pipeline (8 dispatches): prep, hist, scan(+degf), fill,
//   gather(x~)+Sd, fused[agg -> *W1^2 +rank1 -> ReLU -> h],
//   gather(h), fused[agg -> *W2^2 +rank1 -> ReLU -> *Wout + bout -> out].
// All inter-stage tensors bf16; fp32 accumulation; gathers unroll-8.
// ---------------------------------------------------------------------------

static inline int ceil_div(int a, int b) { return (a + b - 1) / b; }

typedef __attribute__((ext_vector_type(8))) short bf16x8;  // MFMA A/B frag
typedef __attribute__((ext_vector_type(4))) float f32x4;   // MFMA C/D frag

__device__ inline unsigned short f2bf(float f) {   // fp32 -> bf16 RNE
    unsigned u = __float_as_uint(f);
    return (unsigned short)((u + 0x7fffu + ((u >> 16) & 1u)) >> 16);
}

// ---------------- prep ------------------------------------------------------
// - zero cursor/stat
// - x -> bf16 (x~)
// - W1^2, W2^2 as bf16 MFMA B-fragments (each frag element = fp32 dot of
//   W row k with W col col); Wout as plain bf16 fragments.
// - c1 = b1^T W1, c2 = b2^T W2 (fp32 vectors for the rank-1 terms).
// Frag layout: t = ((ct*4+c)*64+lane)*8+j <-> k = c*32+(lane>>4)*8+j,
//   col = ct*16+(lane&15).

__global__ __launch_bounds__(256) void prep_kernel(const float* __restrict__ x,
                                                   const float* __restrict__ W1,
                                                   const float* __restrict__ b1,
                                                   const float* __restrict__ W2,
                                                   const float* __restrict__ b2,
                                                   const float* __restrict__ Wout,
                                                   unsigned short* __restrict__ xb,
                                                   unsigned short* __restrict__ W1sq,
                                                   unsigned short* __restrict__ W2sq,
                                                   unsigned short* __restrict__ Wof,
                                                   float* __restrict__ c1,
                                                   float* __restrict__ c2,
                                                   int* __restrict__ cursor,
                                                   unsigned* __restrict__ stat,
                                                   int N, int nChunks) {
    int g0 = blockIdx.x * 256 + threadIdx.x;
    int G = gridDim.x * 256;
    for (int i = g0; i < N; i += G) cursor[i] = 0;
    for (int i = g0; i < nChunks; i += G) stat[i] = 0;

    int nq = N * 32;   // float4 count of x
    for (int i = g0; i < nq; i += G) {
        float4 v = ((const float4*)x)[i];
        ushort4 o;
        o.x = f2bf(v.x); o.y = f2bf(v.y); o.z = f2bf(v.z); o.w = f2bf(v.w);
        ((ushort4*)xb)[i] = o;
    }

    for (int t = g0; t < 16384; t += G) {   // W1^2 frags
        int j = t & 7, lane = (t >> 3) & 63, f = t >> 9;
        int c = f & 3, ct = f >> 2;
        int k = c * 32 + (lane >> 4) * 8 + j;
        int col = ct * 16 + (lane & 15);
        float s = 0.f;
        for (int u = 0; u < 128; ++u) s += W1[k * 128 + u] * W1[u * 128 + col];
        W1sq[t] = f2bf(s);
    }
    for (int t = g0; t < 16384; t += G) {   // W2^2 frags
        int j = t & 7, lane = (t >> 3) & 63, f = t >> 9;
        int c = f & 3, ct = f >> 2;
        int k = c * 32 + (lane >> 4) * 8 + j;
        int col = ct * 16 + (lane & 15);
        float s = 0.f;
        for (int u = 0; u < 128; ++u) s += W2[k * 128 + u] * W2[u * 128 + col];
        W2sq[t] = f2bf(s);
    }
    for (int t = g0; t < 8192; t += G) {    // Wout frags (plain)
        int j = t & 7, lane = (t >> 3) & 63, f = t >> 9;
        int c = f & 3, ct = f >> 2;
        int k = c * 32 + (lane >> 4) * 8 + j;
        int col = ct * 16 + (lane & 15);
        Wof[t] = f2bf(Wout[k * 64 + col]);
    }
    for (int col = g0; col < 128; col += G) {
        float s1 = 0.f, s2 = 0.f;
        for (int k = 0; k < 128; ++k) {
            s1 += b1[k] * W1[k * 128 + col];
            s2 += b2[k] * W2[k * 128 + col];
        }
        c1[col] = s1;
        c2[col] = s2;
    }
}

// ---------------- CSR build ----------------

__global__ __launch_bounds__(256) void hist_kernel(const int* __restrict__ dst,
                                                   int* __restrict__ deg, int E) {
    int e = blockIdx.x * 256 + threadIdx.x;
    if (e < E) atomicAdd(&deg[dst[e]], 1);
}

// Merged scan: publish chunk total (flagged), spin-read predecessors
// (publishers never wait -> no deadlock). Writes rp, seeds cursor, degf.
__global__ __launch_bounds__(256) void scan_fuse_kernel(const int* __restrict__ deg,
                                                        int* __restrict__ rp,
                                                        int* __restrict__ cursor,
                                                        float* __restrict__ degf,
                                                        unsigned* __restrict__ stat,
                                                        int N) {
    __shared__ int s[256];
    int c = blockIdx.x, tid = threadIdx.x;
    int i = c * 256 + tid;
    int v = (i < N) ? deg[i] : 0;
    s[tid] = v;
    __syncthreads();
    for (int off = 1; off < 256; off <<= 1) {
        int t = (tid >= off) ? s[tid - off] : 0;
        __syncthreads();
        s[tid] += t;
        __syncthreads();
    }
    int loc = s[tid] - v;
    int tot = s[255];
    __syncthreads();
    if (tid == 0) atomicExch(&stat[c], (unsigned)tot | 0x80000000u);

    unsigned mine = 0;
    if (tid < c) {
        unsigned u;
        do { u = atomicAdd(&stat[tid], 0u); } while (!(u & 0x80000000u));
        mine = u & 0x7fffffffu;
    }
    s[tid] = (int)mine;
    __syncthreads();
    for (int off = 128; off >= 1; off >>= 1) {
        if (tid < off) s[tid] += s[tid + off];
        __syncthreads();
    }
    int prefix = s[0];
    if (i <= N) {
        int val = loc + prefix;
        rp[i] = val;
        if (i < N) {
            cursor[i] = val;
            degf[i] = (float)v;
        }
    }
}

__global__ __launch_bounds__(256) void fill_kernel(const int* __restrict__ src,
                                                   const int* __restrict__ dst,
                                                   int* __restrict__ cursor,
                                                   int* __restrict__ es, int E) {
    int e = blockIdx.x * 256 + threadIdx.x;
    if (e < E) {
        int p = atomicAdd(&cursor[dst[e]], 1);
        es[p] = src[e];
    }
}

// ---------------- gather: H[i,:] = sum_e M[es[e],:]; optional Sd ------------
// 16 lanes/node, 16 nodes/block, uint4 = 8 bf16/lane; unroll-8 edge loop.

__device__ inline void acc_row8(float* a, uint4 v) {
    a[0] += __uint_as_float(v.x << 16);
    a[1] += __uint_as_float(v.x & 0xffff0000u);
    a[2] += __uint_as_float(v.y << 16);
    a[3] += __uint_as_float(v.y & 0xffff0000u);
    a[4] += __uint_as_float(v.z << 16);
    a[5] += __uint_as_float(v.z & 0xffff0000u);
    a[6] += __uint_as_float(v.w << 16);
    a[7] += __uint_as_float(v.w & 0xffff0000u);
}

template <bool WITH_SD>
__global__ __launch_bounds__(256) void gather_kernel(const unsigned short* __restrict__ M,
                                                     const int* __restrict__ rp,
                                                     const int* __restrict__ es,
                                                     const float* __restrict__ degf,
                                                     unsigned short* __restrict__ Hout,
                                                     float* __restrict__ Sd, int n) {
    int node = blockIdx.x * 16 + (threadIdx.x >> 4);
    int ln = threadIdx.x & 15;
    if (node >= n) return;
    int beg = rp[node], end = rp[node + 1];
    float acc[8] = {};
    float sd = 0.f;
    int e = beg;
    for (; e + 8 <= end; e += 8) {
        int s0 = es[e],     s1 = es[e + 1], s2 = es[e + 2], s3 = es[e + 3];
        int s4 = es[e + 4], s5 = es[e + 5], s6 = es[e + 6], s7 = es[e + 7];
        uint4 v0 = ((const uint4*)(M + (size_t)s0 * 128))[ln];
        uint4 v1 = ((const uint4*)(M + (size_t)s1 * 128))[ln];
        uint4 v2 = ((const uint4*)(M + (size_t)s2 * 128))[ln];
        uint4 v3 = ((const uint4*)(M + (size_t)s3 * 128))[ln];
        uint4 v4 = ((const uint4*)(M + (size_t)s4 * 128))[ln];
        uint4 v5 = ((const uint4*)(M + (size_t)s5 * 128))[ln];
        uint4 v6 = ((const uint4*)(M + (size_t)s6 * 128))[ln];
        uint4 v7 = ((const uint4*)(M + (size_t)s7 * 128))[ln];
        if (WITH_SD)
            sd += degf[s0] + degf[s1] + degf[s2] + degf[s3] +
                  degf[s4] + degf[s5] + degf[s6] + degf[s7];
        acc_row8(acc, v0); acc_row8(acc, v1); acc_row8(acc, v2); acc_row8(acc, v3);
        acc_row8(acc, v4); acc_row8(acc, v5); acc_row8(acc, v6); acc_row8(acc, v7);
    }
    for (; e + 4 <= end; e += 4) {
        int s0 = es[e], s1 = es[e + 1], s2 = es[e + 2], s3 = es[e + 3];
        uint4 v0 = ((const uint4*)(M + (size_t)s0 * 128))[ln];
        uint4 v1 = ((const uint4*)(M + (size_t)s1 * 128))[ln];
        uint4 v2 = ((const uint4*)(M + (size_t)s2 * 128))[ln];
        uint4 v3 = ((const uint4*)(M + (size_t)s3 * 128))[ln];
        if (WITH_SD) sd += degf[s0] + degf[s1] + degf[s2] + degf[s3];
        acc_row8(acc, v0); acc_row8(acc, v1); acc_row8(acc, v2); acc_row8(acc, v3);
    }
    for (; e < end; ++e) {
        int s0 = es[e];
        uint4 v = ((const uint4*)(M + (size_t)s0 * 128))[ln];
        if (WITH_SD) sd += degf[s0];
        acc_row8(acc, v);
    }
    uint4 o;
    o.x = (unsigned)f2bf(acc[0]) | ((unsigned)f2bf(acc[1]) << 16);
    o.y = (unsigned)f2bf(acc[2]) | ((unsigned)f2bf(acc[3]) << 16);
    o.z = (unsigned)f2bf(acc[4]) | ((unsigned)f2bf(acc[5]) << 16);
    o.w = (unsigned)f2bf(acc[6]) | ((unsigned)f2bf(acc[7]) << 16);
    *(uint4*)(Hout + (size_t)node * 128 + ln * 8) = o;
    if (WITH_SD && ln == 0) Sd[node] = sd;
}

// ---------------- fused: agg -> LDS -> *Wsq + Sd*c + d*b -> ReLU ------------
// Block owns 64 nodes; phase A aggregates into LDS (stride 136, 2-way = free);
// phase B: 4 waves, 64x128 MFMA tile, A from LDS, W frags streamed.

__device__ inline void agg_tile_to_lds(const unsigned short* __restrict__ M,
                                       const int* __restrict__ rp,
                                       const int* __restrict__ es,
                                       unsigned short* __restrict__ Hl,
                                       int r0, int n, int tid) {
    constexpr int SR = 136;
    int sub = tid >> 4, ln = tid & 15;
#pragma unroll 1
    for (int q = 0; q < 4; ++q) {
        int nl = sub * 4 + q;
        int node = r0 + nl;
        float acc[8] = {};
        if (node < n) {
            int beg = rp[node], end = rp[node + 1];
            int e = beg;
            for (; e + 8 <= end; e += 8) {
                int s0 = es[e],     s1 = es[e + 1], s2 = es[e + 2], s3 = es[e + 3];
                int s4 = es[e + 4], s5 = es[e + 5], s6 = es[e + 6], s7 = es[e + 7];
                uint4 v0 = ((const uint4*)(M + (size_t)s0 * 128))[ln];
                uint4 v1 = ((const uint4*)(M + (size_t)s1 * 128))[ln];
                uint4 v2 = ((const uint4*)(M + (size_t)s2 * 128))[ln];
                uint4 v3 = ((const uint4*)(M + (size_t)s3 * 128))[ln];
                uint4 v4 = ((const uint4*)(M + (size_t)s4 * 128))[ln];
                uint4 v5 = ((const uint4*)(M + (size_t)s5 * 128))[ln];
                uint4 v6 = ((const uint4*)(M + (size_t)s6 * 128))[ln];
                uint4 v7 = ((const uint4*)(M + (size_t)s7 * 128))[ln];
                acc_row8(acc, v0); acc_row8(acc, v1); acc_row8(acc, v2); acc_row8(acc, v3);
                acc_row8(acc, v4); acc_row8(acc, v5); acc_row8(acc, v6); acc_row8(acc, v7);
            }
            for (; e + 4 <= end; e += 4) {
                int s0 = es[e], s1 = es[e + 1], s2 = es[e + 2], s3 = es[e + 3];
                uint4 v0 = ((const uint4*)(M + (size_t)s0 * 128))[ln];
                uint4 v1 = ((const uint4*)(M + (size_t)s1 * 128))[ln];
                uint4 v2 = ((const uint4*)(M + (size_t)s2 * 128))[ln];
                uint4 v3 = ((const uint4*)(M + (size_t)s3 * 128))[ln];
                acc_row8(acc, v0); acc_row8(acc, v1); acc_row8(acc, v2); acc_row8(acc, v3);
            }
            for (; e < end; ++e) {
                uint4 v = ((const uint4*)(M + (size_t)es[e] * 128))[ln];
                acc_row8(acc, v);
            }
        }
        uint4 o;
        o.x = (unsigned)f2bf(acc[0]) | ((unsigned)f2bf(acc[1]) << 16);
        o.y = (unsigned)f2bf(acc[2]) | ((unsigned)f2bf(acc[3]) << 16);
        o.z = (unsigned)f2bf(acc[4]) | ((unsigned)f2bf(acc[5]) << 16);
        o.w = (unsigned)f2bf(acc[6]) | ((unsigned)f2bf(acc[7]) << 16);
        *(uint4*)(&Hl[nl * SR + ln * 8]) = o;
    }
}

__global__ __launch_bounds__(256) void fused_pool_gemm_kernel(const unsigned short* __restrict__ M,
                                                              const int* __restrict__ rp,
                                                              const int* __restrict__ es,
                                                              const uint4* __restrict__ Wf,
                                                              const float* __restrict__ cvec,
                                                              const float* __restrict__ bvec,
                                                              const float* __restrict__ Sd,
                                                              const float* __restrict__ degf,
                                                              unsigned short* __restrict__ Y,
                                                              int n) {
    constexpr int SR = 136;
    __shared__ unsigned short Hl[64 * SR];
    int tid = threadIdx.x, r0 = blockIdx.x * 64;

    agg_tile_to_lds(M, rp, es, Hl, r0, n, tid);
    __syncthreads();

    int wave = tid >> 6, lane = tid & 63;
    int lm = lane & 15, lq = lane >> 4;

    f32x4 acc[4][2];
#pragma unroll
    for (int rt = 0; rt < 4; ++rt)
#pragma unroll
        for (int t = 0; t < 2; ++t)
            acc[rt][t] = (f32x4){0.f, 0.f, 0.f, 0.f};

#pragma unroll
    for (int c = 0; c < 4; ++c) {
        bf16x8 afr[4];
#pragma unroll
        for (int rt = 0; rt < 4; ++rt)
            afr[rt] = *(const bf16x8*)(&Hl[(rt * 16 + lm) * SR + c * 32 + lq * 8]);
#pragma unroll
        for (int t = 0; t < 2; ++t) {
            int ct = wave * 2 + t;
            uint4 uh = Wf[(ct * 4 + c) * 64 + lane];
            bf16x8 wh = *(const bf16x8*)&uh;
#pragma unroll
            for (int rt = 0; rt < 4; ++rt)
                acc[rt][t] = __builtin_amdgcn_mfma_f32_16x16x32_bf16(afr[rt], wh, acc[rt][t], 0, 0, 0);
        }
    }

    // epilogue: + Sd*c + d*b, ReLU, bf16 store. C/D: col=lane&15, row=lq*4+reg
#pragma unroll
    for (int t = 0; t < 2; ++t) {
        int col = (wave * 2 + t) * 16 + lm;
        float cv = cvec[col], bv = bvec[col];
#pragma unroll
        for (int rt = 0; rt < 4; ++rt) {
#pragma unroll
            for (int r = 0; r < 4; ++r) {
                int row = r0 + rt * 16 + lq * 4 + r;
                if (row < n) {
                    float v = acc[rt][t][r] + Sd[row] * cv + degf[row] * bv;
                    Y[(size_t)row * 128 + col] = f2bf(fmaxf(v, 0.f));
                }
            }
        }
    }
}

// ---------------- fused final: agg -> *W2sq +rank1 -> ReLU -> *Wout -> out --

__global__ __launch_bounds__(256) void fused_pool_gemm_out_kernel(const unsigned short* __restrict__ M,
                                                                  const int* __restrict__ rp,
                                                                  const int* __restrict__ es,
                                                                  const uint4* __restrict__ Wf,
                                                                  const float* __restrict__ cvec,
                                                                  const float* __restrict__ bvec,
                                                                  const float* __restrict__ Sd,
                                                                  const float* __restrict__ degf,
                                                                  const uint4* __restrict__ Wof,
                                                                  const float* __restrict__ bout,
                                                                  float* __restrict__ out,
                                                                  int n) {
    constexpr int SR = 136;
    __shared__ unsigned short Hl[64 * SR];
    int tid = threadIdx.x, r0 = blockIdx.x * 64;

    agg_tile_to_lds(M, rp, es, Hl, r0, n, tid);
    __syncthreads();

    int wave = tid >> 6, lane = tid & 63;
    int lm = lane & 15, lq = lane >> 4;

    f32x4 acc[4][2];
#pragma unroll
    for (int rt = 0; rt < 4; ++rt)
#pragma unroll
        for (int t = 0; t < 2; ++t)
            acc[rt][t] = (f32x4){0.f, 0.f, 0.f, 0.f};

#pragma unroll
    for (int c = 0; c < 4; ++c) {
        bf16x8 afr[4];
#pragma unroll
        for (int rt = 0; rt < 4; ++rt)
            afr[rt] = *(const bf16x8*)(&Hl[(rt * 16 + lm) * SR + c * 32 + lq * 8]);
#pragma unroll
        for (int t = 0; t < 2; ++t) {
            int ct = wave * 2 + t;
            uint4 uh = Wf[(ct * 4 + c) * 64 + lane];
            bf16x8 wh = *(const bf16x8*)&uh;
#pragma unroll
            for (int rt = 0; rt < 4; ++rt)
                acc[rt][t] = __builtin_amdgcn_mfma_f32_16x16x32_bf16(afr[rt], wh, acc[rt][t], 0, 0, 0);
        }
    }

    __syncthreads();   // all Hl A-frag reads done before overwrite

    // epilogue1: rank-1 + ReLU, write g-tile (bf16) back into Hl
#pragma unroll
    for (int t = 0; t < 2; ++t) {
        int col = (wave * 2 + t) * 16 + lm;
        float cv = cvec[col], bv = bvec[col];
#pragma unroll
        for (int rt = 0; rt < 4; ++rt) {
#pragma unroll
            for (int r = 0; r < 4; ++r) {
                int rowl = rt * 16 + lq * 4 + r;
                int row = r0 + rowl;
                float sdv = 0.f, dv = 0.f;
                if (row < n) { sdv = Sd[row]; dv = degf[row]; }
                float v = acc[rt][t][r] + sdv * cv + dv * bv;
                Hl[rowl * SR + col] = f2bf(fmaxf(v, 0.f));
            }
        }
    }
    __syncthreads();

    // phase C: out-tile GEMM (64 x 64): wave = col-tile
    f32x4 acc2[4];
#pragma unroll
    for (int rt = 0; rt < 4; ++rt) acc2[rt] = (f32x4){0.f, 0.f, 0.f, 0.f};

#pragma unroll
    for (int c = 0; c < 4; ++c) {
        bf16x8 afr[4];
#pragma unroll
        for (int rt = 0; rt < 4; ++rt)
            afr[rt] = *(const bf16x8*)(&Hl[(rt * 16 + lm) * SR + c * 32 + lq * 8]);
        uint4 uw = Wof[(wave * 4 + c) * 64 + lane];
        bf16x8 wf = *(const bf16x8*)&uw;
#pragma unroll
        for (int rt = 0; rt < 4; ++rt)
            acc2[rt] = __builtin_amdgcn_mfma_f32_16x16x32_bf16(afr[rt], wf, acc2[rt], 0, 0, 0);
    }

    int col = wave * 16 + lm;
    float bo = bout[col];
#pragma unroll
    for (int rt = 0; rt < 4; ++rt) {
#pragma unroll
        for (int r = 0; r < 4; ++r) {
            int row = r0 + rt * 16 + lq * 4 + r;
            if (row < n) out[(size_t)row * 64 + col] = acc2[rt][r] + bo;
        }
    }
}

// ---------------- Launch ----------------

extern "C" void kernel_launch(void* const* d_in, const int* in_sizes, int n_in,
                              void* d_out, int out_size, void* d_ws, size_t ws_size,
                              hipStream_t stream) {
    const float* x    = (const float*)d_in[0];
    const int*   ei   = (const int*)d_in[1];
    const float* W1   = (const float*)d_in[2];
    const float* b1   = (const float*)d_in[3];
    const float* W2   = (const float*)d_in[4];
    const float* b2   = (const float*)d_in[5];
    const float* Wout = (const float*)d_in[6];
    const float* bout = (const float*)d_in[7];
    float*       out  = (float*)d_out;

    const int N = in_sizes[0] / 128;
    const int E = in_sizes[1] / 2;
    const int* src = ei;
    const int* dst = ei + E;

    char* ws = (char*)d_ws;
    auto take = [&](size_t bytes) {
        char* p = ws;
        ws += (bytes + 255) & ~(size_t)255;
        return p;
    };
    unsigned short* xb = (unsigned short*)take((size_t)N * 128 * 2);
    unsigned short* g1 = (unsigned short*)take((size_t)N * 128 * 2);
    unsigned short* h  = (unsigned short*)take((size_t)N * 128 * 2);
    unsigned short* g3 = (unsigned short*)take((size_t)N * 128 * 2);
    unsigned short* W1sq = (unsigned short*)take(128 * 128 * 2);
    unsigned short* W2sq = (unsigned short*)take(128 * 128 * 2);
    unsigned short* Wof  = (unsigned short*)take(128 * 64 * 2);
    float* c1   = (float*)take(128 * 4);
    float* c2   = (float*)take(128 * 4);
    float* Sd   = (float*)take((size_t)N * 4);
    float* degf = (float*)take((size_t)N * 4);
    int* rp      = (int*)take((size_t)(N + 1) * sizeof(int));
    int* cursor  = (int*)take((size_t)N * sizeof(int));
    int* es      = (int*)take((size_t)E * sizeof(int));
    unsigned* stat = (unsigned*)take(4096);

    const int nChunks = ceil_div(N + 1, 256);   // 196 for N=50000 (<=256 required)
    const int tiles   = ceil_div(N, 64);
    const int ggrid   = ceil_div(N, 16);

    prep_kernel<<<256, 256, 0, stream>>>(x, W1, b1, W2, b2, Wout, xb, W1sq, W2sq,
                                         Wof, c1, c2, cursor, stat, N, nChunks);
    hist_kernel<<<ceil_div(E, 256), 256, 0, stream>>>(dst, cursor, E);
    scan_fuse_kernel<<<nChunks, 256, 0, stream>>>(cursor, rp, cursor, degf, stat, N);
    fill_kernel<<<ceil_div(E, 256), 256, 0, stream>>>(src, dst, cursor, es, E);

    gather_kernel<true><<<ggrid, 256, 0, stream>>>(xb, rp, es, degf, g1, Sd, N);
    fused_pool_gemm_kernel<<<tiles, 256, 0, stream>>>(
        g1, rp, es, (const uint4*)W1sq, c1, b1, Sd, degf, h, N);
    gather_kernel<false><<<ggrid, 256, 0, stream>>>(h, rp, es, degf, g3, nullptr, N);
    fused_pool_gemm_out_kernel<<<tiles, 256, 0, stream>>>(
        g3, rp, es, (const uint4*)W2sq, c2, b2, Sd, degf,
        (const uint4*)Wof, bout, out, N);
}

// Round 9
// 299.650 us; speedup vs baseline: 1.0806x; 1.0806x over previous
//
#include <hip/hip_runtime.h>

// ---------------------------------------------------------------------------
// GraphTransformerWithPooling on MI355X (gfx950)
// R9: revert R8's algebraic collapse (gather count is invariant at 4; it only
// un-fused gather from GEMM). R7 pipeline shape plus:
//  - fused agg+GEMM tiles shrunk 64->32 nodes (grid 782->1563, ~6 blocks/CU):
//    the gather is latency-bound at 3 blocks/CU (R8: Occupancy 17%).
//  - es[] stored as ushort (N < 65536): halves fill-scatter + index traffic.
//  - fill and gemm1 split again (R7's merged kernel was 66 us > sum of parts).
// 9 dispatches: prep, hist, scan_fuse, fill, gemm1, fused x4.
// bf16 MFMA (16x16x32), single-rounded bf16 W (absmax 16 of 66.24 headroom),
// fp32 accumulation; inter-stage tensors bf16.
// ---------------------------------------------------------------------------

static inline int ceil_div(int a, int b) { return (a + b - 1) / b; }

typedef __attribute__((ext_vector_type(8))) short bf16x8;  // MFMA A/B frag
typedef __attribute__((ext_vector_type(4))) float f32x4;   // MFMA C/D frag

__device__ inline unsigned short f2bf(float f) {   // fp32 -> bf16 RNE
    unsigned u = __float_as_uint(f);
    return (unsigned short)((u + 0x7fffu + ((u >> 16) & 1u)) >> 16);
}

// ---------------- prep: zero cursor/stat, expand W1/W2/Wout into frags ------
// Frag layout t = ((ct*4+c)*64+lane)*8+j <-> k = c*32+(lane>>4)*8+j,
//   col = ct*16+(lane&15); a wave's 16B load of hi[] is the MFMA B fragment.

__device__ void wprep_dev(const float* __restrict__ W, unsigned short* __restrict__ hi,
                          int total, int C, int g0, int G) {
    for (int t = g0; t < total; t += G) {
        int j = t & 7;
        int lane = (t >> 3) & 63;
        int f = t >> 9;
        int c = f & 3, ct = f >> 2;
        int k = c * 32 + (lane >> 4) * 8 + j;
        int col = ct * 16 + (lane & 15);
        hi[t] = f2bf(W[(size_t)k * C + col]);
    }
}

__global__ __launch_bounds__(256) void prep_kernel(const float* __restrict__ W1,
                                                   const float* __restrict__ W2,
                                                   const float* __restrict__ Wout,
                                                   unsigned short* __restrict__ W1hi,
                                                   unsigned short* __restrict__ W2hi,
                                                   unsigned short* __restrict__ Wohi,
                                                   int* __restrict__ cursor,
                                                   unsigned* __restrict__ stat,
                                                   int N, int nChunks) {
    int g0 = blockIdx.x * 256 + threadIdx.x;
    int G = gridDim.x * 256;
    for (int i = g0; i < N; i += G) cursor[i] = 0;
    for (int i = g0; i < nChunks; i += G) stat[i] = 0;
    wprep_dev(W1, W1hi, 128 * 128, 128, g0, G);
    wprep_dev(W2, W2hi, 128 * 128, 128, g0, G);
    wprep_dev(Wout, Wohi, 128 * 64, 64, g0, G);
}

// ---------------- CSR build ----------------

__global__ __launch_bounds__(256) void hist_kernel(const int* __restrict__ dst,
                                                   int* __restrict__ deg, int E) {
    int e = blockIdx.x * 256 + threadIdx.x;
    if (e < E) atomicAdd(&deg[dst[e]], 1);
}

// Merged scan: publish chunk total (flag bit), spin-read predecessors
// (publishers never wait -> no deadlock). Writes rp, seeds fill cursor.
__global__ __launch_bounds__(256) void scan_fuse_kernel(const int* __restrict__ deg,
                                                        int* __restrict__ rp,
                                                        int* __restrict__ cursor,
                                                        unsigned* __restrict__ stat,
                                                        int N) {
    __shared__ int s[256];
    int c = blockIdx.x, tid = threadIdx.x;
    int i = c * 256 + tid;
    int v = (i < N) ? deg[i] : 0;
    s[tid] = v;
    __syncthreads();
    for (int off = 1; off < 256; off <<= 1) {
        int t = (tid >= off) ? s[tid - off] : 0;
        __syncthreads();
        s[tid] += t;
        __syncthreads();
    }
    int loc = s[tid] - v;
    int tot = s[255];
    __syncthreads();
    if (tid == 0) atomicExch(&stat[c], (unsigned)tot | 0x80000000u);

    unsigned mine = 0;
    if (tid < c) {
        unsigned u;
        do { u = atomicAdd(&stat[tid], 0u); } while (!(u & 0x80000000u));
        mine = u & 0x7fffffffu;
    }
    s[tid] = (int)mine;
    __syncthreads();
    for (int off = 128; off >= 1; off >>= 1) {
        if (tid < off) s[tid] += s[tid + off];
        __syncthreads();
    }
    int prefix = s[0];
    if (i <= N) {
        int val = loc + prefix;
        rp[i] = val;
        if (i < N) cursor[i] = val;
    }
}

__global__ __launch_bounds__(256) void fill_kernel(const int* __restrict__ src,
                                                   const int* __restrict__ dst,
                                                   int* __restrict__ cursor,
                                                   unsigned short* __restrict__ es, int E) {
    int e = blockIdx.x * 256 + threadIdx.x;
    if (e < E) {
        int p = atomicAdd(&cursor[dst[e]], 1);
        es[p] = (unsigned short)src[e];
    }
}

// ---------------- GEMM1: Y[n,128] = bf16(X_f32)[n,128] @ W1 + b1 -> bf16 ----
// 64 rows/block, 4 waves, no LDS, W frags streamed (L2-hot).

__global__ __launch_bounds__(256) void gemm1_kernel(const float* __restrict__ X,
                                                    const uint4* __restrict__ Whi,
                                                    const float* __restrict__ Bias,
                                                    unsigned short* __restrict__ Y, int n) {
    int tid = threadIdx.x;
    int wave = tid >> 6, lane = tid & 63;
    int lm = lane & 15, lq = lane >> 4;
    int r0 = blockIdx.x * 64;

    bf16x8 afr[4][4];
#pragma unroll
    for (int rt = 0; rt < 4; ++rt) {
        int ar = r0 + rt * 16 + lm;
        if (ar > n - 1) ar = n - 1;
#pragma unroll
        for (int c = 0; c < 4; ++c) {
            int k = c * 32 + lq * 8;
            const float* ap = X + (size_t)ar * 128 + k;
            float4 f0 = ((const float4*)ap)[0];
            float4 f1 = ((const float4*)ap)[1];
            bf16x8 v;
            v[0] = (short)f2bf(f0.x); v[1] = (short)f2bf(f0.y);
            v[2] = (short)f2bf(f0.z); v[3] = (short)f2bf(f0.w);
            v[4] = (short)f2bf(f1.x); v[5] = (short)f2bf(f1.y);
            v[6] = (short)f2bf(f1.z); v[7] = (short)f2bf(f1.w);
            afr[rt][c] = v;
        }
    }

    f32x4 acc[4][2];
#pragma unroll
    for (int rt = 0; rt < 4; ++rt)
#pragma unroll
        for (int t = 0; t < 2; ++t)
            acc[rt][t] = (f32x4){0.f, 0.f, 0.f, 0.f};

#pragma unroll
    for (int c = 0; c < 4; ++c) {
#pragma unroll
        for (int t = 0; t < 2; ++t) {
            int ct = wave * 2 + t;
            uint4 uh = Whi[(ct * 4 + c) * 64 + lane];
            bf16x8 wh = *(const bf16x8*)&uh;
#pragma unroll
            for (int rt = 0; rt < 4; ++rt)
                acc[rt][t] = __builtin_amdgcn_mfma_f32_16x16x32_bf16(afr[rt][c], wh, acc[rt][t], 0, 0, 0);
        }
    }

#pragma unroll
    for (int t = 0; t < 2; ++t) {
        int col = (wave * 2 + t) * 16 + lm;
        float bias = Bias[col];
#pragma unroll
        for (int rt = 0; rt < 4; ++rt) {
#pragma unroll
            for (int r = 0; r < 4; ++r) {
                int row = r0 + rt * 16 + lq * 4 + r;
                if (row < n)
                    Y[(size_t)row * 128 + col] = f2bf(acc[rt][t][r] + bias);
            }
        }
    }
}

// ---------------- Fused aggregate + GEMM (32-node tiles) --------------------
// Block owns 32 nodes. Phase A: 16 lane-groups aggregate 2 nodes each
// (gather bf16 rows of M, fp32 acc, optional ReLU) -> LDS (stride 136,
// 2-way bank aliasing = free). Phase B: 4 waves, 32xCOLS MFMA tile
// (2 row-tiles x CT_W col-tiles per wave), A from LDS, W frags streamed.

__device__ inline void acc_row8(float* a, uint4 v) {
    a[0] += __uint_as_float(v.x << 16);
    a[1] += __uint_as_float(v.x & 0xffff0000u);
    a[2] += __uint_as_float(v.y << 16);
    a[3] += __uint_as_float(v.y & 0xffff0000u);
    a[4] += __uint_as_float(v.z << 16);
    a[5] += __uint_as_float(v.z & 0xffff0000u);
    a[6] += __uint_as_float(v.w << 16);
    a[7] += __uint_as_float(v.w & 0xffff0000u);
}

template <int COLS, bool OUTF32>
__global__ __launch_bounds__(256) void fused_agg_gemm_kernel(const unsigned short* __restrict__ M,
                                                             const int* __restrict__ rp,
                                                             const unsigned short* __restrict__ es,
                                                             const uint4* __restrict__ Whi,
                                                             const float* __restrict__ Bias,
                                                             void* __restrict__ Yv,
                                                             int n, int do_relu) {
    constexpr int CT_W = COLS / 64;            // col-tiles per wave (128->2, 64->1)
    constexpr int SR = 136;                    // LDS row stride in bf16
    __shared__ unsigned short Hl[32 * SR];

    int tid = threadIdx.x;
    int r0 = blockIdx.x * 32;

    // ---- Phase A: aggregate 32 nodes into LDS ----
    {
        int sub = tid >> 4, ln = tid & 15;
#pragma unroll 1
        for (int q = 0; q < 2; ++q) {
            int nl = sub * 2 + q;
            int node = r0 + nl;
            float acc[8] = {};
            if (node < n) {
                int beg = rp[node], end = rp[node + 1];
                int e = beg;
                for (; e + 8 <= end; e += 8) {
                    int s0 = es[e],     s1 = es[e + 1], s2 = es[e + 2], s3 = es[e + 3];
                    int s4 = es[e + 4], s5 = es[e + 5], s6 = es[e + 6], s7 = es[e + 7];
                    uint4 v0 = ((const uint4*)(M + (size_t)s0 * 128))[ln];
                    uint4 v1 = ((const uint4*)(M + (size_t)s1 * 128))[ln];
                    uint4 v2 = ((const uint4*)(M + (size_t)s2 * 128))[ln];
                    uint4 v3 = ((const uint4*)(M + (size_t)s3 * 128))[ln];
                    uint4 v4 = ((const uint4*)(M + (size_t)s4 * 128))[ln];
                    uint4 v5 = ((const uint4*)(M + (size_t)s5 * 128))[ln];
                    uint4 v6 = ((const uint4*)(M + (size_t)s6 * 128))[ln];
                    uint4 v7 = ((const uint4*)(M + (size_t)s7 * 128))[ln];
                    acc_row8(acc, v0); acc_row8(acc, v1);
                    acc_row8(acc, v2); acc_row8(acc, v3);
                    acc_row8(acc, v4); acc_row8(acc, v5);
                    acc_row8(acc, v6); acc_row8(acc, v7);
                }
                for (; e + 4 <= end; e += 4) {
                    int s0 = es[e], s1 = es[e + 1], s2 = es[e + 2], s3 = es[e + 3];
                    uint4 v0 = ((const uint4*)(M + (size_t)s0 * 128))[ln];
                    uint4 v1 = ((const uint4*)(M + (size_t)s1 * 128))[ln];
                    uint4 v2 = ((const uint4*)(M + (size_t)s2 * 128))[ln];
                    uint4 v3 = ((const uint4*)(M + (size_t)s3 * 128))[ln];
                    acc_row8(acc, v0); acc_row8(acc, v1);
                    acc_row8(acc, v2); acc_row8(acc, v3);
                }
                for (; e < end; ++e) {
                    uint4 v = ((const uint4*)(M + (size_t)es[e] * 128))[ln];
                    acc_row8(acc, v);
                }
                if (do_relu) {
#pragma unroll
                    for (int i = 0; i < 8; ++i) acc[i] = fmaxf(acc[i], 0.f);
                }
            }
            uint4 o;
            o.x = (unsigned)f2bf(acc[0]) | ((unsigned)f2bf(acc[1]) << 16);
            o.y = (unsigned)f2bf(acc[2]) | ((unsigned)f2bf(acc[3]) << 16);
            o.z = (unsigned)f2bf(acc[4]) | ((unsigned)f2bf(acc[5]) << 16);
            o.w = (unsigned)f2bf(acc[6]) | ((unsigned)f2bf(acc[7]) << 16);
            *(uint4*)(&Hl[nl * SR + ln * 8]) = o;
        }
    }
    __syncthreads();

    // ---- Phase B: 32xCOLS MFMA tile, A from LDS ----
    int wave = tid >> 6, lane = tid & 63;
    int lm = lane & 15, lq = lane >> 4;

    f32x4 acc[2][CT_W];
#pragma unroll
    for (int rt = 0; rt < 2; ++rt)
#pragma unroll
        for (int t = 0; t < CT_W; ++t)
            acc[rt][t] = (f32x4){0.f, 0.f, 0.f, 0.f};

#pragma unroll
    for (int c = 0; c < 4; ++c) {
        bf16x8 afr[2];
#pragma unroll
        for (int rt = 0; rt < 2; ++rt)
            afr[rt] = *(const bf16x8*)(&Hl[(rt * 16 + lm) * SR + c * 32 + lq * 8]);
#pragma unroll
        for (int t = 0; t < CT_W; ++t) {
            int ct = wave * CT_W + t;
            uint4 uh = Whi[(ct * 4 + c) * 64 + lane];
            bf16x8 wh = *(const bf16x8*)&uh;
#pragma unroll
            for (int rt = 0; rt < 2; ++rt)
                acc[rt][t] = __builtin_amdgcn_mfma_f32_16x16x32_bf16(afr[rt], wh, acc[rt][t], 0, 0, 0);
        }
    }

    // C/D layout: col = lane&15, row = lq*4 + reg
#pragma unroll
    for (int t = 0; t < CT_W; ++t) {
        int col = (wave * CT_W + t) * 16 + lm;
        float bias = Bias[col];
#pragma unroll
        for (int rt = 0; rt < 2; ++rt) {
#pragma unroll
            for (int r = 0; r < 4; ++r) {
                int row = r0 + rt * 16 + lq * 4 + r;
                if (row < n) {
                    float v = acc[rt][t][r] + bias;
                    if (OUTF32)
                        ((float*)Yv)[(size_t)row * COLS + col] = v;
                    else
                        ((unsigned short*)Yv)[(size_t)row * COLS + col] = f2bf(v);
                }
            }
        }
    }
}

// ---------------- Launch ----------------

extern "C" void kernel_launch(void* const* d_in, const int* in_sizes, int n_in,
                              void* d_out, int out_size, void* d_ws, size_t ws_size,
                              hipStream_t stream) {
    const float* x    = (const float*)d_in[0];
    const int*   ei   = (const int*)d_in[1];
    const float* W1   = (const float*)d_in[2];
    const float* b1   = (const float*)d_in[3];
    const float* W2   = (const float*)d_in[4];
    const float* b2   = (const float*)d_in[5];
    const float* Wout = (const float*)d_in[6];
    const float* bout = (const float*)d_in[7];
    float*       out  = (float*)d_out;

    const int N = in_sizes[0] / 128;
    const int E = in_sizes[1] / 2;
    const int* src = ei;
    const int* dst = ei + E;

    char* ws = (char*)d_ws;
    auto take = [&](size_t bytes) {
        char* p = ws;
        ws += (bytes + 255) & ~(size_t)255;
        return p;
    };
    unsigned short* mA = (unsigned short*)take((size_t)N * 128 * 2);
    unsigned short* mB = (unsigned short*)take((size_t)N * 128 * 2);
    unsigned short* W1hi = (unsigned short*)take(128 * 128 * 2);
    unsigned short* W2hi = (unsigned short*)take(128 * 128 * 2);
    unsigned short* Wohi = (unsigned short*)take(128 * 64 * 2);
    int* rp      = (int*)take((size_t)(N + 1) * sizeof(int));
    int* cursor  = (int*)take((size_t)N * sizeof(int));
    unsigned short* es = (unsigned short*)take((size_t)E * sizeof(unsigned short));
    unsigned* stat = (unsigned*)take(4096);

    const int nChunks = ceil_div(N + 1, 256);   // 196 for N=50000 (<=256 required)
    const int tiles64 = ceil_div(N, 64);
    const int tiles32 = ceil_div(N, 32);

    prep_kernel<<<256, 256, 0, stream>>>(W1, W2, Wout, W1hi, W2hi, Wohi,
                                         cursor, stat, N, nChunks);
    hist_kernel<<<ceil_div(E, 256), 256, 0, stream>>>(dst, cursor, E);
    scan_fuse_kernel<<<nChunks, 256, 0, stream>>>(cursor, rp, cursor, stat, N);
    fill_kernel<<<ceil_div(E, 256), 256, 0, stream>>>(src, dst, cursor, es, E);
    gemm1_kernel<<<tiles64, 256, 0, stream>>>(x, (const uint4*)W1hi, b1, mA, N);

    fused_agg_gemm_kernel<128, false><<<tiles32, 256, 0, stream>>>(
        mA, rp, es, (const uint4*)W1hi, b1, mB, N, 0);
    fused_agg_gemm_kernel<128, false><<<tiles32, 256, 0, stream>>>(
        mB, rp, es, (const uint4*)W2hi, b2, mA, N, 1);   // ReLU(h) then *W2+b2
    fused_agg_gemm_kernel<128, false><<<tiles32, 256, 0, stream>>>(
        mA, rp, es, (const uint4*)W2hi, b2, mB, N, 0);
    fused_agg_gemm_kernel<64, true><<<tiles32, 256, 0, stream>>>(
        mB, rp, es, (const uint4*)Wohi, bout, out, N, 1); // ReLU(h2) then *Wout
}